// Round 16
// baseline (104.919 us; speedup 1.0000x reference)
//
#include <hip/hip_runtime.h>
#include <hip/hip_bf16.h>
#include <stdint.h>

typedef __bf16  bf16x8 __attribute__((ext_vector_type(8)));
typedef __bf16  bf16x4 __attribute__((ext_vector_type(4)));
typedef float   f32x4  __attribute__((ext_vector_type(4)));
typedef uint32_t u32x4 __attribute__((ext_vector_type(4)));

#define S     2048
#define D     128
#define KVBLK 32
#define NQT   32
#define THR2  11.5415603f   // 8 * log2(e)

__device__ __forceinline__ uint32_t cvt_pk(float lo, float hi2) {
    uint32_t u;
    asm("v_cvt_pk_bf16_f32 %0, %1, %2" : "=v"(u) : "v"(lo), "v"(hi2));
    return u;
}
__device__ __forceinline__ float exp2fast(float x) {
    return __builtin_amdgcn_exp2f(x);
}
__device__ __forceinline__ void gl2lds16(const void* g, void* l) {
    __builtin_amdgcn_global_load_lds(
        (const __attribute__((address_space(1))) void*)g,
        (__attribute__((address_space(3))) void*)l, 16, 0, 0);
}

// ============ kernel A: pack K, V^T to bf16 in pre-swizzled LDS image ========
__global__ __launch_bounds__(256) void pack_kv(
    const float* __restrict__ K, const float* __restrict__ V,
    __bf16* __restrict__ Kp, __bf16* __restrict__ Vp)
{
    const int bh = blockIdx.x, t = blockIdx.y;
    const int tid = threadIdx.x;
    const int kv0 = t * KVBLK;

    {   // K: convert into swizzled image
        const float* src = K + ((size_t)bh * S + kv0) * D;
        char* dst = (char*)Kp + ((size_t)(bh * 64 + t)) * 8192;
        #pragma unroll
        for (int cc = 0; cc < 2; ++cc) {
            const int c = cc * 256 + tid;
            const int row = c >> 4, col16 = c & 15;
            const float4 a = *reinterpret_cast<const float4*>(src + row * D + col16 * 8);
            const float4 b = *reinterpret_cast<const float4*>(src + row * D + col16 * 8 + 4);
            bf16x8 o;
            o[0]=(__bf16)a.x; o[1]=(__bf16)a.y; o[2]=(__bf16)a.z; o[3]=(__bf16)a.w;
            o[4]=(__bf16)b.x; o[5]=(__bf16)b.y; o[6]=(__bf16)b.z; o[7]=(__bf16)b.w;
            *reinterpret_cast<bf16x8*>(
                dst + row * 256 + ((col16 * 16) ^ ((row & 15) << 4))) = o;
        }
    }

    __shared__ __bf16 lds[32][136];
    {   // V -> LDS
        const float* src = V + ((size_t)bh * S + kv0) * D;
        #pragma unroll
        for (int it = 0; it < 4; ++it) {
            const int id = it * 256 + tid;
            const int row = id >> 5, c4 = id & 31;
            float4 v = *reinterpret_cast<const float4*>(src + row * D + c4 * 4);
            bf16x4 b4;
            b4[0]=(__bf16)v.x; b4[1]=(__bf16)v.y; b4[2]=(__bf16)v.z; b4[3]=(__bf16)v.w;
            *reinterpret_cast<bf16x4*>(&lds[row][c4 * 4]) = b4;
        }
    }
    __syncthreads();
    {   // transpose out, swizzled Vt image
        char* dst = (char*)Vp + ((size_t)(bh * 64 + t)) * 8192;
        #pragma unroll
        for (int cc = 0; cc < 2; ++cc) {
            const int c = cc * 256 + tid;
            const int d = c >> 2, c8 = c & 3;
            bf16x8 o;
            #pragma unroll
            for (int k = 0; k < 8; ++k) o[k] = lds[c8 * 8 + k][d];
            const int addr = (d >> 1) * 128 +
                ((((d & 1) << 6) + c8 * 16) ^ (((d >> 1) & 3) << 4));
            *reinterpret_cast<bf16x8*>(dst + addr) = o;
        }
    }
}

// ============ kernel B: fused (heavy,light) q-pair attention core ============
__global__ __launch_bounds__(256, 2) void attn_fwd(
    const float* __restrict__ Q, const __bf16* __restrict__ Kp,
    const __bf16* __restrict__ Vp, float* __restrict__ O)
{
    const int bh = blockIdx.x;
    const int y  = blockIdx.y;              // 0..15
    const int qtH = NQT - 1 - y;            // heavy q-tile
    const int qtL = y;                      // light q-tile (prefix of H's kv range)
    const int tid  = threadIdx.x;
    const int w    = tid >> 6;
    const int lane = tid & 63;
    const int r    = lane & 15;
    const int g    = lane >> 4;

    const float* Qh = Q + (size_t)bh * S * D;
    float*       Oh = O + (size_t)bh * S * D;
    const char*  Kbase = (const char*)Kp + (size_t)bh * 64 * 8192;
    const char*  Vbase = (const char*)Vp + (size_t)bh * 64 * 8192;

    const int q0H = qtH * 64 + w * 16;
    const int q0L = qtL * 64 + w * 16;

    __shared__ __align__(16) __bf16 K_sh[2][KVBLK * D];
    __shared__ __align__(16) __bf16 V_sh[2][D * KVBLK];

    const float scale = 0.08838834764831845f * 1.4426950408889634f;

    // ---- Q fragments for both streams ----
    auto load_q = [&](int q0, bf16x8* qf) {
        const float4* qp = reinterpret_cast<const float4*>(
            Qh + (size_t)(q0 + r) * D + g * 8);
        #pragma unroll
        for (int kb = 0; kb < 4; ++kb) {
            float4 a = qp[kb*8 + 0];
            float4 b = qp[kb*8 + 1];
            a.x*=scale; a.y*=scale; a.z*=scale; a.w*=scale;
            b.x*=scale; b.y*=scale; b.z*=scale; b.w*=scale;
            bf16x8 f;
            f[0]=(__bf16)a.x; f[1]=(__bf16)a.y; f[2]=(__bf16)a.z; f[3]=(__bf16)a.w;
            f[4]=(__bf16)b.x; f[5]=(__bf16)b.y; f[6]=(__bf16)b.z; f[7]=(__bf16)b.w;
            qf[kb] = f;
        }
    };
    bf16x8 qfH[4], qfL[4];
    load_q(q0H, qfH);
    load_q(q0L, qfL);

    auto STAGE = [&](int buf, int t) {
        const char* ks = Kbase + (size_t)t * 8192 + w * 1024 + lane * 16;
        const char* vs = Vbase + (size_t)t * 8192 + w * 1024 + lane * 16;
        char* kd = (char*)(&K_sh[buf][0]) + w * 1024;
        char* vd = (char*)(&V_sh[buf][0]) + w * 1024;
        gl2lds16(ks,        kd);
        gl2lds16(ks + 4096, kd + 4096);
        gl2lds16(vs,        vd);
        gl2lds16(vs + 4096, vd + 4096);
    };

    const f32x4 vzero = {0.f, 0.f, 0.f, 0.f};
    f32x4 accH[8], accL[8];
    #pragma unroll
    for (int i = 0; i < 8; ++i) { accH[i] = vzero; accL[i] = vzero; }
    float mH = -1e30f, lH = 0.f, mL = -1e30f, lL = 0.f;

    const int n_iter = 2 * qtH + 2;
    const int maxH = (q0H + 15) >> 5;
    const int maxL = (q0L + 15) >> 5;     // < n_iter always (y<=15)

    // one tile of one stream: QK -> online softmax -> PV
    auto stream_tile = [&](int t, int q0, const bf16x8* qf,
                           f32x4* acc, float& m_run, float& l_run,
                           char* Kb, char* Vb) {
        const int kv0 = t * KVBLK;
        const bool alive1 = (kv0 + 16 <= q0 + 15);

        f32x4 st[2] = {vzero, vzero};
        __builtin_amdgcn_s_setprio(1);
        #pragma unroll
        for (int tt = 0; tt < 2; ++tt) {
            if (tt == 1 && !alive1) break;
            const int row = tt * 16 + r;
            #pragma unroll
            for (int kb = 0; kb < 4; ++kb) {
                bf16x8 kf = *reinterpret_cast<const bf16x8*>(
                    Kb + row * 256 + ((kb*64 + g*16) ^ ((row & 15) << 4)));
                st[tt] = __builtin_amdgcn_mfma_f32_16x16x32_bf16(
                    kf, qf[kb], st[tt], 0, 0, 0);
            }
        }
        __builtin_amdgcn_s_setprio(0);

        const int q = q0 + r;
        float pmax = -1e30f;
        #pragma unroll
        for (int tt = 0; tt < 2; ++tt) {
            if (tt == 1 && !alive1) break;
            if (kv0 + tt*16 + 15 > q0) {
                #pragma unroll
                for (int jj = 0; jj < 4; ++jj)
                    if (kv0 + tt*16 + 4*g + jj > q) st[tt][jj] = -1e30f;
            }
            #pragma unroll
            for (int jj = 0; jj < 4; ++jj) pmax = fmaxf(pmax, st[tt][jj]);
        }
        pmax = fmaxf(pmax, __shfl_xor(pmax, 16));
        pmax = fmaxf(pmax, __shfl_xor(pmax, 32));

        if (__any(pmax > m_run + THR2)) {        // rare (defer-max)
            const float m_new = fmaxf(m_run, pmax);
            const float corr  = exp2fast(m_run - m_new);
            l_run *= corr; m_run = m_new;
            #pragma unroll
            for (int reg = 0; reg < 4; ++reg) {
                const float cr = __shfl(corr, 4*g + reg);
                #pragma unroll
                for (int dt = 0; dt < 8; ++dt) acc[dt][reg] *= cr;
            }
        }

        float rowsum = 0.f;
        #pragma unroll
        for (int tt = 0; tt < 2; ++tt) {
            if (tt == 1 && !alive1) break;
            #pragma unroll
            for (int jj = 0; jj < 4; ++jj) {
                const float p = exp2fast(st[tt][jj] - m_run);
                st[tt][jj] = p;
                rowsum += p;
            }
        }
        rowsum += __shfl_xor(rowsum, 16);
        rowsum += __shfl_xor(rowsum, 32);
        l_run += rowsum;

        const uint32_t p00 = cvt_pk(st[0][0], st[0][1]);
        const uint32_t p01 = cvt_pk(st[0][2], st[0][3]);
        const uint32_t p10 = alive1 ? cvt_pk(st[1][0], st[1][1]) : 0u;
        const uint32_t p11 = alive1 ? cvt_pk(st[1][2], st[1][3]) : 0u;
        const int sA = r + ((2 * (g & 1)) << 4);
        const int sB = r + ((2 * (g & 1) + 1) << 4);
        u32x4 words;
        {
            const uint32_t lo0 = (uint32_t)__shfl((int)p00, sA);
            const uint32_t hi0 = (uint32_t)__shfl((int)p10, sA);
            const uint32_t lo1 = (uint32_t)__shfl((int)p01, sA);
            const uint32_t hi1 = (uint32_t)__shfl((int)p11, sA);
            const uint32_t lo2 = (uint32_t)__shfl((int)p00, sB);
            const uint32_t hi2 = (uint32_t)__shfl((int)p10, sB);
            const uint32_t lo3 = (uint32_t)__shfl((int)p01, sB);
            const uint32_t hi3 = (uint32_t)__shfl((int)p11, sB);
            words[0] = (g & 2) ? hi0 : lo0;
            words[1] = (g & 2) ? hi1 : lo1;
            words[2] = (g & 2) ? hi2 : lo2;
            words[3] = (g & 2) ? hi3 : lo3;
        }
        const bf16x8 pa = __builtin_bit_cast(bf16x8, words);

        __builtin_amdgcn_s_setprio(1);
        #pragma unroll
        for (int dt = 0; dt < 8; ++dt) {
            const int d = dt * 16 + r;
            const int byte = (d >> 1) * 128 +
                ((((d & 1) << 6) + (g << 4)) ^ (((d >> 1) & 3) << 4));
            bf16x8 vf = *reinterpret_cast<const bf16x8*>(Vb + byte);
            acc[dt] = __builtin_amdgcn_mfma_f32_16x16x32_bf16(
                pa, vf, acc[dt], 0, 0, 0);
        }
        __builtin_amdgcn_s_setprio(0);
    };

    STAGE(0, 0);
    __syncthreads();
    int cur = 0;

    for (int t = 0; t < n_iter; ++t) {
        if (t + 1 < n_iter) STAGE(cur ^ 1, t + 1);
        char* Kb = reinterpret_cast<char*>(&K_sh[cur][0]);
        char* Vb = reinterpret_cast<char*>(&V_sh[cur][0]);
        // two independent streams in one barrier region -> dual ILP
        if (t <= maxL) stream_tile(t, q0L, qfL, accL, mL, lL, Kb, Vb);
        if (t <= maxH) stream_tile(t, q0H, qfH, accH, mH, lH, Kb, Vb);
        __syncthreads();
        cur ^= 1;
    }

    // ---- epilogues ----
    auto epilogue = [&](int q0, f32x4* acc, float l_run) {
        const float inv = 1.0f / l_run;
        #pragma unroll
        for (int reg = 0; reg < 4; ++reg) {
            const float iv = __shfl(inv, 4*g + reg);
            float* orow = Oh + (size_t)(q0 + 4*g + reg) * D + r;
            #pragma unroll
            for (int dt = 0; dt < 8; ++dt)
                orow[dt * 16] = acc[dt][reg] * iv;
        }
    };
    epilogue(q0H, accH, lH);
    epilogue(q0L, accL, lL);
}

extern "C" void kernel_launch(void* const* d_in, const int* in_sizes, int n_in,
                              void* d_out, int out_size, void* d_ws, size_t ws_size,
                              hipStream_t stream) {
    const float* Q = (const float*)d_in[0];
    const float* K = (const float*)d_in[1];
    const float* V = (const float*)d_in[2];
    float* O = (float*)d_out;

    __bf16* Kp = (__bf16*)d_ws;
    __bf16* Vp = Kp + (size_t)32 * S * D;

    pack_kv<<<dim3(32, 64), 256, 0, stream>>>(K, V, Kp, Vp);
    attn_fwd<<<dim3(32, 16), 256, 0, stream>>>(Q, Kp, Vp, O);
}

// Round 17
// 93.799 us; speedup vs baseline: 1.1186x; 1.1186x over previous
//
#include <hip/hip_runtime.h>
#include <hip/hip_bf16.h>
#include <stdint.h>

typedef __bf16  bf16x8 __attribute__((ext_vector_type(8)));
typedef __bf16  bf16x4 __attribute__((ext_vector_type(4)));
typedef float   f32x16 __attribute__((ext_vector_type(16)));
typedef uint32_t u32x4 __attribute__((ext_vector_type(4)));

#define S     2048
#define D     128
#define TKV   64            // kv rows per staged tile
#define NQB   16            // q-blocks of 128 per head
#define THR2  11.5415603f   // 8 * log2(e)
#define KROW(reg) ((((reg) & 3) + 8 * ((reg) >> 2)) + 4 * hi)

__device__ __forceinline__ uint32_t cvt_pk(float lo, float hi2) {
    uint32_t u;
    asm("v_cvt_pk_bf16_f32 %0, %1, %2" : "=v"(u) : "v"(lo), "v"(hi2));
    return u;
}
__device__ __forceinline__ float exp2fast(float x) {
    return __builtin_amdgcn_exp2f(x);
}
__device__ __forceinline__ void gl2lds16(const void* g, void* l) {
    __builtin_amdgcn_global_load_lds(
        (const __attribute__((address_space(1))) void*)g,
        (__attribute__((address_space(3))) void*)l, 16, 0, 0);
}

// ====== kernel A: pack K and V^T (bf16) into pre-swizzled 64-kv tile images ==
// pair p = 64-kv tile; K image 16KB: row64*256 + ((d>>3 ^ (row64&15))<<4)
// Vt image 16KB: d*128 + ((kv>>3 ^ (d&7))<<4) + (kv&7)*2
__global__ __launch_bounds__(256) void pack_kv(
    const float* __restrict__ K, const float* __restrict__ V,
    __bf16* __restrict__ Kp, __bf16* __restrict__ Vp)
{
    const int bh = blockIdx.x, t = blockIdx.y;      // t = 32-kv subtile
    const int tid = threadIdx.x;
    const int kv0 = t * 32;
    const int pair = t >> 1, half = t & 1;

    {   // K: convert into swizzled image half
        const float* src = K + ((size_t)bh * S + kv0) * D;
        char* dst = (char*)Kp + ((size_t)(bh * 32 + pair)) * 16384 + half * 8192;
        #pragma unroll
        for (int cc = 0; cc < 2; ++cc) {
            const int c = cc * 256 + tid;           // 0..511 16B chunks
            const int row = c >> 4, col16 = c & 15;
            const float4 a = *reinterpret_cast<const float4*>(src + row * D + col16 * 8);
            const float4 b = *reinterpret_cast<const float4*>(src + row * D + col16 * 8 + 4);
            bf16x8 o;
            o[0]=(__bf16)a.x; o[1]=(__bf16)a.y; o[2]=(__bf16)a.z; o[3]=(__bf16)a.w;
            o[4]=(__bf16)b.x; o[5]=(__bf16)b.y; o[6]=(__bf16)b.z; o[7]=(__bf16)b.w;
            *reinterpret_cast<bf16x8*>(
                dst + row * 256 + ((col16 * 16) ^ ((row & 15) << 4))) = o;
        }
    }

    __shared__ __bf16 lds[32][136];
    {   // V -> LDS
        const float* src = V + ((size_t)bh * S + kv0) * D;
        #pragma unroll
        for (int it = 0; it < 4; ++it) {
            const int id = it * 256 + tid;
            const int row = id >> 5, c4 = id & 31;
            float4 v = *reinterpret_cast<const float4*>(src + row * D + c4 * 4);
            bf16x4 b4;
            b4[0]=(__bf16)v.x; b4[1]=(__bf16)v.y; b4[2]=(__bf16)v.z; b4[3]=(__bf16)v.w;
            *reinterpret_cast<bf16x4*>(&lds[row][c4 * 4]) = b4;
        }
    }
    __syncthreads();
    {   // transpose out: Vt pair image, chunk = half*4 + c8
        char* dst = (char*)Vp + ((size_t)(bh * 32 + pair)) * 16384;
        #pragma unroll
        for (int cc = 0; cc < 2; ++cc) {
            const int c = cc * 256 + tid;           // 0..511
            const int d = c >> 2, c8 = c & 3;
            bf16x8 o;
            #pragma unroll
            for (int k = 0; k < 8; ++k) o[k] = lds[c8 * 8 + k][d];
            const int addr = d * 128 + (((half * 4 + c8) ^ (d & 7)) << 4);
            *reinterpret_cast<bf16x8*>(dst + addr) = o;
        }
    }
}

// ====== kernel B: 4 waves x 32 q-rows, 32x32 MFMA, gload_lds staging ========
__global__ __launch_bounds__(256, 2) void attn_fwd(
    const float* __restrict__ Q, const __bf16* __restrict__ Kp,
    const __bf16* __restrict__ Vp, float* __restrict__ O)
{
    const int bh = blockIdx.x;
    const int qt = (NQB - 1) - blockIdx.y;  // LPT: longest first
    const int tid  = threadIdx.x;
    const int w    = tid >> 6;
    const int lane = tid & 63;
    const int c    = lane & 31;
    const int hi   = lane >> 5;

    const float* Qh = Q + (size_t)bh * S * D;
    float*       Oh = O + (size_t)bh * S * D;
    const char*  Kbase = (const char*)Kp + (size_t)bh * 32 * 16384;
    const char*  Vbase = (const char*)Vp + (size_t)bh * 32 * 16384;

    const int q0w = qt * 128 + w * 32;      // wave's first q row

    __shared__ __align__(16) __bf16 K_sh[2][TKV * D];   // 16KB each
    __shared__ __align__(16) __bf16 V_sh[2][D * TKV];   // 16KB each

    const float scale = 0.08838834764831845f * 1.4426950408889634f;

    // ---- Q fragments (B operand): col = q0w+c, k(d) = ks*16 + hi*8 + e ----
    bf16x8 qfrag[8];
    {
        const float* qrow = Qh + (size_t)(q0w + c) * D;
        #pragma unroll
        for (int ks = 0; ks < 8; ++ks) {
            const int d0 = ks * 16 + hi * 8;
            float4 a = *reinterpret_cast<const float4*>(qrow + d0);
            float4 b = *reinterpret_cast<const float4*>(qrow + d0 + 4);
            a.x*=scale; a.y*=scale; a.z*=scale; a.w*=scale;
            b.x*=scale; b.y*=scale; b.z*=scale; b.w*=scale;
            bf16x8 f;
            f[0]=(__bf16)a.x; f[1]=(__bf16)a.y; f[2]=(__bf16)a.z; f[3]=(__bf16)a.w;
            f[4]=(__bf16)b.x; f[5]=(__bf16)b.y; f[6]=(__bf16)b.z; f[7]=(__bf16)b.w;
            qfrag[ks] = f;
        }
    }

    auto STAGE = [&](int buf, int t64) {
        const char* ks = Kbase + (size_t)t64 * 16384 + w * 4096 + lane * 16;
        const char* vs = Vbase + (size_t)t64 * 16384 + w * 4096 + lane * 16;
        char* kd = (char*)(&K_sh[buf][0]) + w * 4096;   // wave-uniform base
        char* vd = (char*)(&V_sh[buf][0]) + w * 4096;
        #pragma unroll
        for (int i = 0; i < 4; ++i) {
            gl2lds16(ks + i * 1024, kd + i * 1024);
            gl2lds16(vs + i * 1024, vd + i * 1024);
        }
    };

    f32x16 acc_o[4];
    #pragma unroll
    for (int dt = 0; dt < 4; ++dt)
        #pragma unroll
        for (int i = 0; i < 16; ++i) acc_o[dt][i] = 0.f;
    float m_run = -1e30f, l_run = 0.f;

    const int n_iter = 2 * qt + 2;          // 64-kv tiles for this block
    const int my_max = (q0w + 31) >> 6;     // wave's last live tile

    STAGE(0, 0);
    __syncthreads();
    int cur = 0;

    for (int t = 0; t < n_iter; ++t) {
        if (t + 1 < n_iter) STAGE(cur ^ 1, t + 1);   // async across compute

        if (t <= my_max) {
            const int kv0 = t * TKV;
            char* Kb = reinterpret_cast<char*>(&K_sh[cur][0]);
            char* Vb = reinterpret_cast<char*>(&V_sh[cur][0]);
            const bool alive1 = (kv0 + 32 <= q0w + 31);

            // ---- swapped QK^T: S^T[kv][q]; lane owns q = q0w + c ----
            f32x16 st[2];
            __builtin_amdgcn_s_setprio(1);
            #pragma unroll
            for (int sub = 0; sub < 2; ++sub) {
                #pragma unroll
                for (int i = 0; i < 16; ++i) st[sub][i] = 0.f;
                if (sub == 1 && !alive1) break;
                const int row = sub * 32 + c;
                #pragma unroll
                for (int ks = 0; ks < 8; ++ks) {
                    bf16x8 kf = *reinterpret_cast<const bf16x8*>(
                        Kb + row * 256 + (((ks*2 + hi) ^ (row & 15)) << 4));
                    st[sub] = __builtin_amdgcn_mfma_f32_32x32x16_bf16(
                        kf, qfrag[ks], st[sub], 0, 0, 0);
                }
            }
            __builtin_amdgcn_s_setprio(0);

            // ---- mask + in-register online softmax (exp2, defer-max) ----
            const int q = q0w + c;
            float pmax = -1e30f;
            #pragma unroll
            for (int sub = 0; sub < 2; ++sub) {
                if (sub == 1 && !alive1) break;
                if (kv0 + sub*32 + 31 > q0w) {
                    #pragma unroll
                    for (int reg = 0; reg < 16; ++reg)
                        if (kv0 + sub*32 + KROW(reg) > q) st[sub][reg] = -1e30f;
                }
                #pragma unroll
                for (int reg = 0; reg < 16; ++reg)
                    pmax = fmaxf(pmax, st[sub][reg]);
            }
            pmax = fmaxf(pmax, __shfl_xor(pmax, 32));

            if (__any(pmax > m_run + THR2)) {        // rare (defer-max)
                const float m_new = fmaxf(m_run, pmax);
                const float corr  = exp2fast(m_run - m_new);
                l_run *= corr; m_run = m_new;
                #pragma unroll
                for (int reg = 0; reg < 16; ++reg) {
                    const float cr = __shfl(corr, KROW(reg));
                    #pragma unroll
                    for (int dt = 0; dt < 4; ++dt) acc_o[dt][reg] *= cr;
                }
            }

            float rowsum = 0.f;
            #pragma unroll
            for (int sub = 0; sub < 2; ++sub) {
                if (sub == 1 && !alive1) break;
                #pragma unroll
                for (int reg = 0; reg < 16; ++reg) {
                    const float p = exp2fast(st[sub][reg] - m_run);
                    st[sub][reg] = p;
                    rowsum += p;
                }
            }
            rowsum += __shfl_xor(rowsum, 32);
            l_run += rowsum;

            // ---- P redistribute (cvt_pk + shfl_xor 32) + PV ----
            #pragma unroll
            for (int ks = 0; ks < 4; ++ks) {
                if (kv0 + ks*16 > q0w + 31) break;   // dead k-slice
                const int sub = ks >> 1, k1 = (ks & 1) * 8;
                const uint32_t pkA0 = cvt_pk(st[sub][k1+0], st[sub][k1+1]);
                const uint32_t pkA1 = cvt_pk(st[sub][k1+2], st[sub][k1+3]);
                const uint32_t pkB0 = cvt_pk(st[sub][k1+4], st[sub][k1+5]);
                const uint32_t pkB1 = cvt_pk(st[sub][k1+6], st[sub][k1+7]);
                const uint32_t rA0 = (uint32_t)__shfl_xor((int)pkA0, 32);
                const uint32_t rA1 = (uint32_t)__shfl_xor((int)pkA1, 32);
                const uint32_t rB0 = (uint32_t)__shfl_xor((int)pkB0, 32);
                const uint32_t rB1 = (uint32_t)__shfl_xor((int)pkB1, 32);
                u32x4 words;
                words[0] = hi ? rB0 : pkA0;
                words[1] = hi ? rB1 : pkA1;
                words[2] = hi ? pkB0 : rA0;
                words[3] = hi ? pkB1 : rA1;
                const bf16x8 pa = __builtin_bit_cast(bf16x8, words);
                __builtin_amdgcn_s_setprio(1);
                #pragma unroll
                for (int dt = 0; dt < 4; ++dt) {
                    const int d = dt * 32 + c;
                    bf16x8 vf = *reinterpret_cast<const bf16x8*>(
                        Vb + d * 128 + (((ks*2 + hi) ^ (d & 7)) << 4));
                    acc_o[dt] = __builtin_amdgcn_mfma_f32_32x32x16_bf16(
                        pa, vf, acc_o[dt], 0, 0, 0);
                }
                __builtin_amdgcn_s_setprio(0);
            }
        }

        __syncthreads();    // drains gload_lds + publishes next buffer
        cur ^= 1;
    }

    // ---- epilogue: O[q0w + KROW(reg)][dt*32 + c] = acc / l ----
    const float inv = 1.0f / l_run;
    #pragma unroll
    for (int reg = 0; reg < 16; ++reg) {
        const float iv = __shfl(inv, KROW(reg));
        float* orow = Oh + (size_t)(q0w + KROW(reg)) * D + c;
        #pragma unroll
        for (int dt = 0; dt < 4; ++dt)
            orow[dt * 32] = acc_o[dt][reg] * iv;
    }
}

extern "C" void kernel_launch(void* const* d_in, const int* in_sizes, int n_in,
                              void* d_out, int out_size, void* d_ws, size_t ws_size,
                              hipStream_t stream) {
    const float* Q = (const float*)d_in[0];
    const float* K = (const float*)d_in[1];
    const float* V = (const float*)d_in[2];
    float* O = (float*)d_out;

    __bf16* Kp = (__bf16*)d_ws;               // 16MB
    __bf16* Vp = Kp + (size_t)32 * S * D;     // 16MB

    pack_kv<<<dim3(32, 64), 256, 0, stream>>>(K, V, Kp, Vp);
    attn_fwd<<<dim3(32, NQB), 256, 0, stream>>>(Q, Kp, Vp, O);
}